// Round 1
// baseline (176.643 us; speedup 1.0000x reference)
//
#include <hip/hip_runtime.h>

// Sizes (fixed by the problem)
#define B 4
#define TE 512
#define TD 256
#define D 256

#define TWO_LOG2E 2.8853900817779268f   // 2/ln(2)
#define LOG2E     1.4426950408889634f

// ---------------------------------------------------------------------------
// K1: out = (2*log2e) * (A @ W);  A is [M,256] fp32, W is [256,256] fp32.
// Blocks 0..255 -> enc@W_a (M=2048), blocks 256..383 -> dec@U_a (M=1024).
// 8 rows per block, 256 threads (thread = output column).
// ---------------------------------------------------------------------------
__global__ __launch_bounds__(256) void proj_kernel(
    const float* __restrict__ enc, const float* __restrict__ dec,
    const float* __restrict__ Wa,  const float* __restrict__ Ua,
    float* __restrict__ wenc, float* __restrict__ udec)
{
    __shared__ float a_lds[8 * 256];
    const int blk = blockIdx.x;
    const int tid = threadIdx.x;

    const float* A; const float* W; float* O; int row0;
    if (blk < 256) { A = enc; W = Wa; O = wenc; row0 = blk * 8; }
    else           { A = dec; W = Ua; O = udec; row0 = (blk - 256) * 8; }

    #pragma unroll
    for (int i = 0; i < 8; i++)
        a_lds[i * 256 + tid] = A[(row0 + i) * 256 + tid];
    __syncthreads();

    float acc[8];
    #pragma unroll
    for (int r = 0; r < 8; r++) acc[r] = 0.0f;

    for (int d = 0; d < 256; d += 4) {
        const float w0 = W[(d + 0) * 256 + tid];
        const float w1 = W[(d + 1) * 256 + tid];
        const float w2 = W[(d + 2) * 256 + tid];
        const float w3 = W[(d + 3) * 256 + tid];
        #pragma unroll
        for (int r = 0; r < 8; r++) {
            const float4 a4 = *(const float4*)&a_lds[r * 256 + d];
            acc[r] = fmaf(a4.x, w0, acc[r]);
            acc[r] = fmaf(a4.y, w1, acc[r]);
            acc[r] = fmaf(a4.z, w2, acc[r]);
            acc[r] = fmaf(a4.w, w3, acc[r]);
        }
    }

    #pragma unroll
    for (int r = 0; r < 8; r++)
        O[(row0 + r) * 256 + tid] = TWO_LOG2E * acc[r];
}

// tanh contribution: v * rcp(1 + exp2(K*(w+u)));  score term = v - 2*this
__device__ __forceinline__ float qterm(float w, float u, float v) {
    const float E = __builtin_amdgcn_exp2f(w + u);
    const float r = __builtin_amdgcn_rcpf(1.0f + E);
    return v * r;
}

// ---------------------------------------------------------------------------
// K2: fused score + softmax + context. One block handles 2 decoder positions.
// grid = B*TD/2 = 512 blocks, 256 threads (4 waves).
// Phase 1: wave w sweeps e = w, w+4, ...; lane covers d = 4*lane..4*lane+3.
// Phase 2: block softmax over TE=512 per t.
// Phase 3: thread = d, loop over e with broadcast weights.
// ---------------------------------------------------------------------------
__global__ __launch_bounds__(256) void attn_kernel(
    const float* __restrict__ enc,  const float* __restrict__ wenc,
    const float* __restrict__ udec, const float* __restrict__ Va,
    float* __restrict__ ctx, float* __restrict__ aw)
{
    __shared__ float s_lds[2][TE];
    __shared__ float red[256];

    const int tid  = threadIdx.x;
    const int wave = tid >> 6;
    const int lane = tid & 63;
    const int bt0  = blockIdx.x * 2;     // first (b,t) flat index
    const int b    = bt0 >> 8;           // TD = 256

    const float4 vv = *(const float4*)&Va[lane * 4];
    const float4 u0 = *(const float4*)&udec[(bt0 + 0) * 256 + lane * 4];
    const float4 u1 = *(const float4*)&udec[(bt0 + 1) * 256 + lane * 4];
    const float sumv = (vv.x + vv.y) + (vv.z + vv.w);

    const float* wb = wenc + b * TE * 256;

    // ---- Phase 1: scores -------------------------------------------------
    for (int e = wave; e < TE; e += 4) {
        const float4 w4 = *(const float4*)&wb[e * 256 + lane * 4];

        float q0 = qterm(w4.x, u0.x, vv.x);
        q0 += qterm(w4.y, u0.y, vv.y);
        q0 += qterm(w4.z, u0.z, vv.z);
        q0 += qterm(w4.w, u0.w, vv.w);

        float q1 = qterm(w4.x, u1.x, vv.x);
        q1 += qterm(w4.y, u1.y, vv.y);
        q1 += qterm(w4.z, u1.z, vv.z);
        q1 += qterm(w4.w, u1.w, vv.w);

        float p0 = sumv - 2.0f * q0;
        float p1 = sumv - 2.0f * q1;
        #pragma unroll
        for (int m = 32; m > 0; m >>= 1) {
            p0 += __shfl_xor(p0, m, 64);
            p1 += __shfl_xor(p1, m, 64);
        }
        if (lane == 0) { s_lds[0][e] = p0; s_lds[1][e] = p1; }
    }
    __syncthreads();

    // ---- Phase 2: softmax over e, write attention weights ---------------
    for (int tt = 0; tt < 2; tt++) {
        const float x0 = s_lds[tt][tid];
        const float x1 = s_lds[tt][tid + 256];
        red[tid] = fmaxf(x0, x1);
        __syncthreads();
        for (int s = 128; s > 0; s >>= 1) {
            if (tid < s) red[tid] = fmaxf(red[tid], red[tid + s]);
            __syncthreads();
        }
        const float M = red[0];
        __syncthreads();
        const float e0 = __builtin_amdgcn_exp2f((x0 - M) * LOG2E);
        const float e1 = __builtin_amdgcn_exp2f((x1 - M) * LOG2E);
        red[tid] = e0 + e1;
        __syncthreads();
        for (int s = 128; s > 0; s >>= 1) {
            if (tid < s) red[tid] += red[tid + s];
            __syncthreads();
        }
        const float inv = 1.0f / red[0];
        __syncthreads();
        const float w0 = e0 * inv, w1 = e1 * inv;
        s_lds[tt][tid]       = w0;
        s_lds[tt][tid + 256] = w1;
        aw[(bt0 + tt) * TE + tid]       = w0;
        aw[(bt0 + tt) * TE + tid + 256] = w1;
    }
    __syncthreads();

    // ---- Phase 3: context = sum_e w[e] * enc[b,e,:] ---------------------
    const float* eb = enc + b * TE * 256;
    float acc0 = 0.0f, acc1 = 0.0f;
    #pragma unroll 8
    for (int e = 0; e < TE; e++) {
        const float r = eb[e * 256 + tid];
        acc0 = fmaf(s_lds[0][e], r, acc0);
        acc1 = fmaf(s_lds[1][e], r, acc1);
    }
    ctx[(bt0 + 0) * 256 + tid] = acc0;
    ctx[(bt0 + 1) * 256 + tid] = acc1;
}

extern "C" void kernel_launch(void* const* d_in, const int* in_sizes, int n_in,
                              void* d_out, int out_size, void* d_ws, size_t ws_size,
                              hipStream_t stream) {
    const float* enc = (const float*)d_in[0];   // [4,512,256]
    const float* dec = (const float*)d_in[1];   // [4,256,256]
    const float* Wa  = (const float*)d_in[2];   // [256,256]
    const float* Ua  = (const float*)d_in[3];   // [256,256]
    const float* Va  = (const float*)d_in[4];   // [256,1]

    float* out = (float*)d_out;
    float* ctx = out;                           // [4,256,256] = 262144
    float* aw  = out + B * TD * D;              // [4,256,512] = 524288

    float* wenc = (float*)d_ws;                 // [4,512,256] scaled
    float* udec = wenc + B * TE * D;            // [4,256,256] scaled

    proj_kernel<<<dim3(384), dim3(256), 0, stream>>>(enc, dec, Wa, Ua, wenc, udec);
    attn_kernel<<<dim3(B * TD / 2), dim3(256), 0, stream>>>(enc, wenc, udec, Va, ctx, aw);
}

// Round 2
// 139.918 us; speedup vs baseline: 1.2625x; 1.2625x over previous
//
#include <hip/hip_runtime.h>

// Sizes (fixed by the problem)
#define B 4
#define TE 512
#define TD 256
#define D 256

#define TWO_LOG2E 2.8853900817779268f   // 2/ln(2)
#define LOG2E     1.4426950408889634f

// ---------------------------------------------------------------------------
// K1: out = (2*log2e) * (A @ W);  A is [M,256] fp32, W is [256,256] fp32.
// Blocks 0..511 -> enc@W_a (M=2048), blocks 512..767 -> dec@U_a (M=1024).
// 4 rows per block (768 blocks => 3 blocks/CU, 12 waves/CU).
// ---------------------------------------------------------------------------
__global__ __launch_bounds__(256) void proj_kernel(
    const float* __restrict__ enc, const float* __restrict__ dec,
    const float* __restrict__ Wa,  const float* __restrict__ Ua,
    float* __restrict__ wenc, float* __restrict__ udec)
{
    __shared__ float a_lds[4 * 256];
    const int blk = blockIdx.x;
    const int tid = threadIdx.x;

    const float* A; const float* W; float* O; int row0;
    if (blk < 512) { A = enc; W = Wa; O = wenc; row0 = blk * 4; }
    else           { A = dec; W = Ua; O = udec; row0 = (blk - 512) * 4; }

    #pragma unroll
    for (int i = 0; i < 4; i++)
        a_lds[i * 256 + tid] = A[(row0 + i) * 256 + tid];
    __syncthreads();

    float acc[4] = {0.f, 0.f, 0.f, 0.f};

    #pragma unroll 4
    for (int d = 0; d < 256; d += 4) {
        const float w0 = W[(d + 0) * 256 + tid];
        const float w1 = W[(d + 1) * 256 + tid];
        const float w2 = W[(d + 2) * 256 + tid];
        const float w3 = W[(d + 3) * 256 + tid];
        #pragma unroll
        for (int r = 0; r < 4; r++) {
            const float4 a4 = *(const float4*)&a_lds[r * 256 + d];
            acc[r] = fmaf(a4.x, w0, acc[r]);
            acc[r] = fmaf(a4.y, w1, acc[r]);
            acc[r] = fmaf(a4.z, w2, acc[r]);
            acc[r] = fmaf(a4.w, w3, acc[r]);
        }
    }

    #pragma unroll
    for (int r = 0; r < 4; r++)
        O[(row0 + r) * 256 + tid] = TWO_LOG2E * acc[r];
}

// ---------------------------------------------------------------------------
// K2a: raw scores.  score[b,t,e] = sumv - 2 * sum_d v_d / (1 + Ew_d * Eu_d)
// where Ew = exp2((2/ln2) Wenc), Eu = exp2((2/ln2) Udec).  Ew shared across
// the block's 2 decoder positions (saves 25% of transcendentals).
// grid = 1024: blockIdx = (t-pair 0..511) * 2 + e-half. 4 waves/SIMD TLP.
// Raw scores written into the aw region of d_out; K2b normalizes in place.
// ---------------------------------------------------------------------------
__global__ __launch_bounds__(256) void score_kernel(
    const float* __restrict__ wenc, const float* __restrict__ udec,
    const float* __restrict__ Va,   float* __restrict__ sc)
{
    const int tid  = threadIdx.x;
    const int wave = tid >> 6;
    const int lane = tid & 63;
    const int bt0  = (blockIdx.x >> 1) * 2;   // first (b,t) flat index
    const int e0   = (blockIdx.x & 1) << 8;   // 0 or 256
    const int b    = bt0 >> 8;                // TD = 256

    const float4 vv = *(const float4*)&Va[lane * 4];
    const float4 u0 = *(const float4*)&udec[(bt0 + 0) * 256 + lane * 4];
    const float4 u1 = *(const float4*)&udec[(bt0 + 1) * 256 + lane * 4];
    const float sumv = (vv.x + vv.y) + (vv.z + vv.w);

    float4 Eu0, Eu1;
    Eu0.x = __builtin_amdgcn_exp2f(u0.x); Eu0.y = __builtin_amdgcn_exp2f(u0.y);
    Eu0.z = __builtin_amdgcn_exp2f(u0.z); Eu0.w = __builtin_amdgcn_exp2f(u0.w);
    Eu1.x = __builtin_amdgcn_exp2f(u1.x); Eu1.y = __builtin_amdgcn_exp2f(u1.y);
    Eu1.z = __builtin_amdgcn_exp2f(u1.z); Eu1.w = __builtin_amdgcn_exp2f(u1.w);

    const float* wb = wenc + b * TE * 256;

    for (int e = e0 + wave; e < e0 + 256; e += 4) {
        const float4 w4 = *(const float4*)&wb[e * 256 + lane * 4];
        float4 Ew;
        Ew.x = __builtin_amdgcn_exp2f(w4.x);
        Ew.y = __builtin_amdgcn_exp2f(w4.y);
        Ew.z = __builtin_amdgcn_exp2f(w4.z);
        Ew.w = __builtin_amdgcn_exp2f(w4.w);

        float q0, q1;
        q0  = vv.x * __builtin_amdgcn_rcpf(fmaf(Ew.x, Eu0.x, 1.0f));
        q0 += vv.y * __builtin_amdgcn_rcpf(fmaf(Ew.y, Eu0.y, 1.0f));
        q0 += vv.z * __builtin_amdgcn_rcpf(fmaf(Ew.z, Eu0.z, 1.0f));
        q0 += vv.w * __builtin_amdgcn_rcpf(fmaf(Ew.w, Eu0.w, 1.0f));

        q1  = vv.x * __builtin_amdgcn_rcpf(fmaf(Ew.x, Eu1.x, 1.0f));
        q1 += vv.y * __builtin_amdgcn_rcpf(fmaf(Ew.y, Eu1.y, 1.0f));
        q1 += vv.z * __builtin_amdgcn_rcpf(fmaf(Ew.z, Eu1.z, 1.0f));
        q1 += vv.w * __builtin_amdgcn_rcpf(fmaf(Ew.w, Eu1.w, 1.0f));

        float p0 = sumv - 2.0f * q0;
        float p1 = sumv - 2.0f * q1;
        #pragma unroll
        for (int m = 32; m > 0; m >>= 1) {
            p0 += __shfl_xor(p0, m, 64);
            p1 += __shfl_xor(p1, m, 64);
        }
        if (lane == 0) {
            sc[(bt0 + 0) * TE + e] = p0;
            sc[(bt0 + 1) * TE + e] = p1;
        }
    }
}

// ---------------------------------------------------------------------------
// K2b: softmax over e (in-place on aw) + context.  One block per 2 decoder
// positions (512 blocks) so each enc row read is used for both t's.
// Context: float4 loads, 4 e-rows per iteration, LDS cross-group reduce.
// ---------------------------------------------------------------------------
__global__ __launch_bounds__(256) void softmax_ctx_kernel(
    const float* __restrict__ enc, float* __restrict__ aw,
    float* __restrict__ ctx)
{
    __shared__ float wlds[2][TE];
    __shared__ float red[256];
    __shared__ float part[4][64][8];

    const int tid = threadIdx.x;
    const int bt0 = blockIdx.x * 2;
    const int b   = bt0 >> 8;

    // ---- softmax (scores currently stored in aw) ------------------------
    for (int tt = 0; tt < 2; tt++) {
        const float x0 = aw[(bt0 + tt) * TE + tid];
        const float x1 = aw[(bt0 + tt) * TE + tid + 256];
        red[tid] = fmaxf(x0, x1);
        __syncthreads();
        for (int s = 128; s > 0; s >>= 1) {
            if (tid < s) red[tid] = fmaxf(red[tid], red[tid + s]);
            __syncthreads();
        }
        const float M = red[0];
        __syncthreads();
        const float e0 = __builtin_amdgcn_exp2f((x0 - M) * LOG2E);
        const float e1 = __builtin_amdgcn_exp2f((x1 - M) * LOG2E);
        red[tid] = e0 + e1;
        __syncthreads();
        for (int s = 128; s > 0; s >>= 1) {
            if (tid < s) red[tid] += red[tid + s];
            __syncthreads();
        }
        const float inv = 1.0f / red[0];
        __syncthreads();
        const float w0 = e0 * inv, w1 = e1 * inv;
        wlds[tt][tid]       = w0;
        wlds[tt][tid + 256] = w1;
        aw[(bt0 + tt) * TE + tid]       = w0;
        aw[(bt0 + tt) * TE + tid + 256] = w1;
    }
    __syncthreads();

    // ---- context: thread = (e-group, col4) ------------------------------
    const int eg = tid >> 6;
    const int c4 = tid & 63;
    const float4* eb4 = (const float4*)(enc + b * TE * 256);

    float4 a0 = {0.f, 0.f, 0.f, 0.f};
    float4 a1 = {0.f, 0.f, 0.f, 0.f};
    #pragma unroll 2
    for (int e4 = 0; e4 < TE; e4 += 4) {
        const int e = e4 + eg;
        const float4 r = eb4[e * 64 + c4];
        const float w0 = wlds[0][e];
        const float w1 = wlds[1][e];
        a0.x = fmaf(w0, r.x, a0.x); a0.y = fmaf(w0, r.y, a0.y);
        a0.z = fmaf(w0, r.z, a0.z); a0.w = fmaf(w0, r.w, a0.w);
        a1.x = fmaf(w1, r.x, a1.x); a1.y = fmaf(w1, r.y, a1.y);
        a1.z = fmaf(w1, r.z, a1.z); a1.w = fmaf(w1, r.w, a1.w);
    }
    *(float4*)&part[eg][c4][0] = a0;
    *(float4*)&part[eg][c4][4] = a1;
    __syncthreads();

    if (tid < 64) {
        float4 s0 = *(float4*)&part[0][tid][0];
        float4 s1 = *(float4*)&part[0][tid][4];
        #pragma unroll
        for (int g = 1; g < 4; g++) {
            const float4 p0 = *(float4*)&part[g][tid][0];
            const float4 p1 = *(float4*)&part[g][tid][4];
            s0.x += p0.x; s0.y += p0.y; s0.z += p0.z; s0.w += p0.w;
            s1.x += p1.x; s1.y += p1.y; s1.z += p1.z; s1.w += p1.w;
        }
        ((float4*)ctx)[(bt0 + 0) * 64 + tid] = s0;
        ((float4*)ctx)[(bt0 + 1) * 64 + tid] = s1;
    }
}

extern "C" void kernel_launch(void* const* d_in, const int* in_sizes, int n_in,
                              void* d_out, int out_size, void* d_ws, size_t ws_size,
                              hipStream_t stream) {
    const float* enc = (const float*)d_in[0];   // [4,512,256]
    const float* dec = (const float*)d_in[1];   // [4,256,256]
    const float* Wa  = (const float*)d_in[2];   // [256,256]
    const float* Ua  = (const float*)d_in[3];   // [256,256]
    const float* Va  = (const float*)d_in[4];   // [256,1]

    float* out = (float*)d_out;
    float* ctx = out;                           // [4,256,256] = 262144
    float* aw  = out + B * TD * D;              // [4,256,512] = 524288

    float* wenc = (float*)d_ws;                 // [4,512,256] scaled by 2/ln2
    float* udec = wenc + B * TE * D;            // [4,256,256] scaled by 2/ln2

    proj_kernel<<<dim3(768), dim3(256), 0, stream>>>(enc, dec, Wa, Ua, wenc, udec);
    score_kernel<<<dim3(1024), dim3(256), 0, stream>>>(wenc, udec, Va, aw);
    softmax_ctx_kernel<<<dim3(B * TD / 2), dim3(256), 0, stream>>>(enc, aw, ctx);
}

// Round 3
// 132.969 us; speedup vs baseline: 1.3285x; 1.0523x over previous
//
#include <hip/hip_runtime.h>

#define B 4
#define TE 512
#define TD 256
#define D 256

#define C2    2.8853900817779268f   // 2/ln(2): exp(2x) = exp2(C2*x)
#define LOG2E 1.4426950408889634f

// ---------------------------------------------------------------------------
// K1: projections + exp2, with the enc side stored TRANSPOSED.
//   ewt[b][d][e] = exp2(C2 * (enc@W_a)[b][e][d])     [4][256][512]
//   eu [b][t][d] = exp2(C2 * (dec@U_a)[b][t][d])     [4][256][256]
// Blocks 0..255: enc (8 e-rows each). Blocks 256..383: dec (8 t-rows each).
// A-operand addresses are wave-uniform -> scalar loads (no LDS for A).
// ---------------------------------------------------------------------------
__global__ __launch_bounds__(256) void proj_kernel(
    const float* __restrict__ enc, const float* __restrict__ dec,
    const float* __restrict__ Wa,  const float* __restrict__ Ua,
    float* __restrict__ ewt, float* __restrict__ eu)
{
    __shared__ float tl[8][260];     // transpose staging (enc blocks only)
    const int tid = threadIdx.x;
    const int blk = blockIdx.x;
    const bool is_enc = blk < 256;
    const float* __restrict__ A = is_enc ? enc : dec;
    const float* __restrict__ W = is_enc ? Wa  : Ua;
    const int row0 = (is_enc ? blk : blk - 256) * 8;

    float acc[8] = {0.f,0.f,0.f,0.f,0.f,0.f,0.f,0.f};

    #pragma unroll 4
    for (int k = 0; k < 256; k++) {
        const float w = W[k * 256 + tid];          // coalesced, thread = out col
        #pragma unroll
        for (int r = 0; r < 8; r++)                // A[..] is wave-uniform
            acc[r] = fmaf(A[(row0 + r) * 256 + k], w, acc[r]);
    }

    float ex[8];
    #pragma unroll
    for (int r = 0; r < 8; r++)
        ex[r] = __builtin_amdgcn_exp2f(acc[r] * C2);

    if (is_enc) {
        #pragma unroll
        for (int r = 0; r < 8; r++) tl[r][tid] = ex[r];   // conflict-free
        __syncthreads();
        float f[8];
        #pragma unroll
        for (int j = 0; j < 8; j++) f[j] = tl[j][tid];    // conflict-free
        const int b  = row0 >> 9;
        const int e0 = row0 & 511;
        float* o = ewt + ((size_t)(b * 256 + tid)) * 512 + e0;
        float4 p0 = make_float4(f[0], f[1], f[2], f[3]);
        float4 p1 = make_float4(f[4], f[5], f[6], f[7]);
        *(float4*)o       = p0;
        *(float4*)(o + 4) = p1;
    } else {
        #pragma unroll
        for (int r = 0; r < 8; r++)
            eu[(row0 + r) * 256 + tid] = ex[r];
    }
}

// ---------------------------------------------------------------------------
// K2: fused score + softmax + context. One block per (b, t-pair): 512 blocks.
// Score: thread = e-pair (2*tid, 2*tid+1); d-reduction entirely in-register.
//   score[t][e] = sum_d v_d - 2 * sum_d v_d / (1 + Ew[d][e]*Eu[t][d])
// Softmax: block reduction over TE=512 (2 values/thread).
// Context: thread = d, weights broadcast from LDS via b128 reads.
// ---------------------------------------------------------------------------
__global__ __launch_bounds__(256) void attn_kernel(
    const float* __restrict__ enc, const float* __restrict__ ewt,
    const float* __restrict__ eu,  const float* __restrict__ Va,
    float* __restrict__ ctx, float* __restrict__ aw)
{
    __shared__ float wlds[2][TE];
    __shared__ float red[256];

    const int tid = threadIdx.x;
    const int b   = blockIdx.x >> 7;
    const int t0  = (blockIdx.x & 127) * 2;

    const float* __restrict__ ew   = ewt + (size_t)b * 256 * 512;
    const float* __restrict__ eu0p = eu + ((b << 8) + t0) * 256;
    const float* __restrict__ eu1p = eu0p + 256;

    float s00 = 0.f, s01 = 0.f, s10 = 0.f, s11 = 0.f, sv = 0.f;

    #pragma unroll 4
    for (int d = 0; d < 256; d++) {
        const float2 w2 = *(const float2*)&ew[d * 512 + tid * 2];  // coalesced
        const float a  = eu0p[d];       // wave-uniform
        const float c  = eu1p[d];       // wave-uniform
        const float vd = Va[d];         // wave-uniform
        sv  += vd;
        s00 += vd * __builtin_amdgcn_rcpf(fmaf(w2.x, a, 1.0f));
        s01 += vd * __builtin_amdgcn_rcpf(fmaf(w2.y, a, 1.0f));
        s10 += vd * __builtin_amdgcn_rcpf(fmaf(w2.x, c, 1.0f));
        s11 += vd * __builtin_amdgcn_rcpf(fmaf(w2.y, c, 1.0f));
    }

    float x00 = sv - 2.0f * s00, x01 = sv - 2.0f * s01;
    float x10 = sv - 2.0f * s10, x11 = sv - 2.0f * s11;

    #pragma unroll
    for (int tt = 0; tt < 2; tt++) {
        const float y0 = tt ? x10 : x00;
        const float y1 = tt ? x11 : x01;
        red[tid] = fmaxf(y0, y1);
        __syncthreads();
        for (int s = 128; s > 0; s >>= 1) {
            if (tid < s) red[tid] = fmaxf(red[tid], red[tid + s]);
            __syncthreads();
        }
        const float M = red[0];
        __syncthreads();
        const float g0 = __builtin_amdgcn_exp2f((y0 - M) * LOG2E);
        const float g1 = __builtin_amdgcn_exp2f((y1 - M) * LOG2E);
        red[tid] = g0 + g1;
        __syncthreads();
        for (int s = 128; s > 0; s >>= 1) {
            if (tid < s) red[tid] += red[tid + s];
            __syncthreads();
        }
        const float inv = __builtin_amdgcn_rcpf(red[0]);
        __syncthreads();
        const float w0 = g0 * inv, w1 = g1 * inv;
        wlds[tt][2 * tid]     = w0;
        wlds[tt][2 * tid + 1] = w1;
        ((float2*)aw)[((b << 8) + t0 + tt) * 256 + tid] = make_float2(w0, w1);
    }
    __syncthreads();

    // ---- context: thread = d ----
    const float* __restrict__ eb = enc + (size_t)b * TE * 256;
    float a0 = 0.f, a1 = 0.f;
    #pragma unroll 2
    for (int e = 0; e < TE; e += 4) {
        const float4 w0 = *(const float4*)&wlds[0][e];
        const float4 w1 = *(const float4*)&wlds[1][e];
        const float r0 = eb[(e + 0) * 256 + tid];
        const float r1 = eb[(e + 1) * 256 + tid];
        const float r2 = eb[(e + 2) * 256 + tid];
        const float r3 = eb[(e + 3) * 256 + tid];
        a0 = fmaf(w0.x, r0, a0); a0 = fmaf(w0.y, r1, a0);
        a0 = fmaf(w0.z, r2, a0); a0 = fmaf(w0.w, r3, a0);
        a1 = fmaf(w1.x, r0, a1); a1 = fmaf(w1.y, r1, a1);
        a1 = fmaf(w1.z, r2, a1); a1 = fmaf(w1.w, r3, a1);
    }
    ctx[((b << 8) + t0 + 0) * 256 + tid] = a0;
    ctx[((b << 8) + t0 + 1) * 256 + tid] = a1;
}

extern "C" void kernel_launch(void* const* d_in, const int* in_sizes, int n_in,
                              void* d_out, int out_size, void* d_ws, size_t ws_size,
                              hipStream_t stream) {
    const float* enc = (const float*)d_in[0];   // [4,512,256]
    const float* dec = (const float*)d_in[1];   // [4,256,256]
    const float* Wa  = (const float*)d_in[2];   // [256,256]
    const float* Ua  = (const float*)d_in[3];   // [256,256]
    const float* Va  = (const float*)d_in[4];   // [256,1]

    float* out = (float*)d_out;
    float* ctx = out;                           // [4,256,256] = 262144
    float* aw  = out + B * TD * D;              // [4,256,512] = 524288

    float* ewt = (float*)d_ws;                  // [4][256 d][512 e] = 2 MB
    float* eu  = ewt + (size_t)B * D * TE;      // [4][256 t][256 d] = 1 MB

    proj_kernel<<<dim3(384), dim3(256), 0, stream>>>(enc, dec, Wa, Ua, ewt, eu);
    attn_kernel<<<dim3(B * TD / 2), dim3(256), 0, stream>>>(enc, ewt, eu, Va, ctx, aw);
}

// Round 5
// 117.480 us; speedup vs baseline: 1.5036x; 1.1318x over previous
//
#include <hip/hip_runtime.h>

#define B 4
#define TE 512
#define TD 256
#define D 256

#define C2    2.8853900817779268f   // 2/ln(2): exp(2x) = exp2(C2*x)
#define LOG2E 1.4426950408889634f

__device__ __forceinline__ void fma4(float4& acc, float s, const float4& v) {
    acc.x = fmaf(s, v.x, acc.x);
    acc.y = fmaf(s, v.y, acc.y);
    acc.z = fmaf(s, v.z, acc.z);
    acc.w = fmaf(s, v.w, acc.w);
}

// ---------------------------------------------------------------------------
// K1: projections + exp2.  O = A @ W, then ewt[b][d][e] = exp2(C2*O) stored
// TRANSPOSED for the enc side; eu[b][t][d] = exp2(C2*O) for the dec side.
// Blocks 0..511: enc (4 e-rows each).  Blocks 512..767: dec (4 t-rows each).
// Thread = (ks = k-quarter, cg = col-quad). Register tile 4 rows x 4 cols.
// A via LDS b128 broadcasts, W via coalesced float4 vector loads: no
// scalar-path (s_load) traffic in the inner loop.
// ---------------------------------------------------------------------------
__global__ __launch_bounds__(256) void proj_kernel(
    const float* __restrict__ enc, const float* __restrict__ dec,
    const float* __restrict__ Wa,  const float* __restrict__ Ua,
    float* __restrict__ ewt, float* __restrict__ eu)
{
    __shared__ float a_lds[4][256];
    __shared__ float part[4][64][4][4];   // [ks][cg][r][c] = 16 KB

    const int tid = threadIdx.x;
    const int blk = blockIdx.x;
    const bool is_enc = blk < 512;
    const float* __restrict__ A = is_enc ? enc : dec;
    const float* __restrict__ W = is_enc ? Wa  : Ua;
    const int row0 = (is_enc ? blk : blk - 512) * 4;

    {   // stage the 4 A rows (coalesced float4)
        const int r  = tid >> 6;
        const int c4 = (tid & 63) * 4;
        *(float4*)&a_lds[r][c4] = *(const float4*)&A[(row0 + r) * 256 + c4];
    }
    __syncthreads();

    const int ks = tid >> 6;       // k-quarter: k in [64*ks, 64*ks+64)
    const int cg = tid & 63;       // cols 4*cg .. 4*cg+3
    const int k0 = ks * 64;

    float4 acc0 = {0,0,0,0}, acc1 = {0,0,0,0}, acc2 = {0,0,0,0}, acc3 = {0,0,0,0};

    #pragma unroll 4
    for (int g = 0; g < 16; g++) {
        const int k = k0 + g * 4;
        const float4 w0 = *(const float4*)&W[(k + 0) * 256 + cg * 4];
        const float4 w1 = *(const float4*)&W[(k + 1) * 256 + cg * 4];
        const float4 w2 = *(const float4*)&W[(k + 2) * 256 + cg * 4];
        const float4 w3 = *(const float4*)&W[(k + 3) * 256 + cg * 4];
        const float4 a0 = *(const float4*)&a_lds[0][k];
        const float4 a1 = *(const float4*)&a_lds[1][k];
        const float4 a2 = *(const float4*)&a_lds[2][k];
        const float4 a3 = *(const float4*)&a_lds[3][k];
        fma4(acc0, a0.x, w0); fma4(acc0, a0.y, w1); fma4(acc0, a0.z, w2); fma4(acc0, a0.w, w3);
        fma4(acc1, a1.x, w0); fma4(acc1, a1.y, w1); fma4(acc1, a1.z, w2); fma4(acc1, a1.w, w3);
        fma4(acc2, a2.x, w0); fma4(acc2, a2.y, w1); fma4(acc2, a2.z, w2); fma4(acc2, a2.w, w3);
        fma4(acc3, a3.x, w0); fma4(acc3, a3.y, w1); fma4(acc3, a3.z, w2); fma4(acc3, a3.w, w3);
    }

    *(float4*)&part[ks][cg][0][0] = acc0;
    *(float4*)&part[ks][cg][1][0] = acc1;
    *(float4*)&part[ks][cg][2][0] = acc2;
    *(float4*)&part[ks][cg][3][0] = acc3;
    __syncthreads();

    {   // k-quarter reduce + exp2 + store
        const int r   = tid >> 6;
        const int cg2 = tid & 63;
        float4 f = {0,0,0,0};
        #pragma unroll
        for (int q = 0; q < 4; q++) {
            const float4 p = *(const float4*)&part[q][cg2][r][0];
            f.x += p.x; f.y += p.y; f.z += p.z; f.w += p.w;
        }
        f.x = __builtin_amdgcn_exp2f(f.x * C2);
        f.y = __builtin_amdgcn_exp2f(f.y * C2);
        f.z = __builtin_amdgcn_exp2f(f.z * C2);
        f.w = __builtin_amdgcn_exp2f(f.w * C2);
        if (is_enc) {
            const int b = row0 >> 9;
            const int e = (row0 & 511) + r;
            float* o = ewt + ((size_t)(b * 256 + cg2 * 4)) * 512 + e;
            o[0 * 512] = f.x; o[1 * 512] = f.y; o[2 * 512] = f.z; o[3 * 512] = f.w;
        } else {
            *(float4*)&eu[(row0 + r) * 256 + cg2 * 4] = f;
        }
    }
}

// ---------------------------------------------------------------------------
// K2: raw scores.  score[t][e] = sum_d v_d - 2 * sum_d v_d/(1 + Ew[d][e]*Eu[t][d])
// grid 1024 = (t-pair) x (e-half): 4 blocks/CU, 16 waves/CU.
// thread = e; Eu rows + Va staged in LDS, read as b128 broadcasts.
// ---------------------------------------------------------------------------
__global__ __launch_bounds__(256) void score_kernel(
    const float* __restrict__ ewt, const float* __restrict__ eu,
    const float* __restrict__ Va,  float* __restrict__ raw)
{
    __shared__ float eu0_l[256], eu1_l[256], va_l[256];

    const int tid = threadIdx.x;
    const int tp  = blockIdx.x >> 1;
    const int h   = blockIdx.x & 1;
    const int bt0 = tp * 2;
    const int b   = bt0 >> 8;

    eu0_l[tid] = eu[(bt0 + 0) * 256 + tid];
    eu1_l[tid] = eu[(bt0 + 1) * 256 + tid];
    va_l[tid]  = Va[tid];
    __syncthreads();

    const int e = h * 256 + tid;
    const float* __restrict__ ewb = ewt + (size_t)b * 256 * 512 + e;

    float s0 = 0.f, s1 = 0.f, sv = 0.f;

    #pragma unroll 4
    for (int d = 0; d < 256; d += 4) {
        const float w0 = ewb[(d + 0) * 512];
        const float w1 = ewb[(d + 1) * 512];
        const float w2 = ewb[(d + 2) * 512];
        const float w3 = ewb[(d + 3) * 512];
        const float4 a0 = *(const float4*)&eu0_l[d];
        const float4 a1 = *(const float4*)&eu1_l[d];
        const float4 v4 = *(const float4*)&va_l[d];
        sv += (v4.x + v4.y) + (v4.z + v4.w);
        s0 += v4.x * __builtin_amdgcn_rcpf(fmaf(w0, a0.x, 1.0f));
        s0 += v4.y * __builtin_amdgcn_rcpf(fmaf(w1, a0.y, 1.0f));
        s0 += v4.z * __builtin_amdgcn_rcpf(fmaf(w2, a0.z, 1.0f));
        s0 += v4.w * __builtin_amdgcn_rcpf(fmaf(w3, a0.w, 1.0f));
        s1 += v4.x * __builtin_amdgcn_rcpf(fmaf(w0, a1.x, 1.0f));
        s1 += v4.y * __builtin_amdgcn_rcpf(fmaf(w1, a1.y, 1.0f));
        s1 += v4.z * __builtin_amdgcn_rcpf(fmaf(w2, a1.z, 1.0f));
        s1 += v4.w * __builtin_amdgcn_rcpf(fmaf(w3, a1.w, 1.0f));
    }

    raw[(bt0 + 0) * 512 + e] = sv - 2.0f * s0;
    raw[(bt0 + 1) * 512 + e] = sv - 2.0f * s1;
}

// ---------------------------------------------------------------------------
// K3: softmax (redundant per d-half; only dh==0 writes aw) + context.
// grid 1024 = (t-pair) x (d-half): 16 waves/CU.
// Context: thread = (e-group, d-lane); enc reads coalesced; weights b128
// broadcasts from LDS; 2-way e-group reduce through LDS.
// ---------------------------------------------------------------------------
__global__ __launch_bounds__(256) void sctx_kernel(
    const float* __restrict__ enc, const float* __restrict__ raw,
    float* __restrict__ ctx, float* __restrict__ aw)
{
    __shared__ float wlds[2][TE];
    __shared__ float red[256];
    __shared__ float part[2][128][2];

    const int tid = threadIdx.x;
    const int tp  = blockIdx.x >> 1;
    const int dh  = blockIdx.x & 1;
    const int bt0 = tp * 2;
    const int b   = bt0 >> 8;

    #pragma unroll
    for (int tt = 0; tt < 2; tt++) {
        const float x0 = raw[(bt0 + tt) * 512 + tid];
        const float x1 = raw[(bt0 + tt) * 512 + tid + 256];
        red[tid] = fmaxf(x0, x1);
        __syncthreads();
        for (int s = 128; s > 0; s >>= 1) {
            if (tid < s) red[tid] = fmaxf(red[tid], red[tid + s]);
            __syncthreads();
        }
        const float M = red[0];
        __syncthreads();
        const float g0 = __builtin_amdgcn_exp2f((x0 - M) * LOG2E);
        const float g1 = __builtin_amdgcn_exp2f((x1 - M) * LOG2E);
        red[tid] = g0 + g1;
        __syncthreads();
        for (int s = 128; s > 0; s >>= 1) {
            if (tid < s) red[tid] += red[tid + s];
            __syncthreads();
        }
        const float inv = __builtin_amdgcn_rcpf(red[0]);
        __syncthreads();
        const float w0 = g0 * inv, w1 = g1 * inv;
        wlds[tt][tid]       = w0;
        wlds[tt][tid + 256] = w1;
        if (dh == 0) {
            aw[(bt0 + tt) * 512 + tid]       = w0;
            aw[(bt0 + tt) * 512 + tid + 256] = w1;
        }
    }
    __syncthreads();

    // context: eg covers 256 e's; d-lane covers this block's 128 d's
    const int eg = tid >> 7;
    const int dl = tid & 127;
    const float* __restrict__ eb = enc + (size_t)b * TE * 256 + dh * 128 + dl;
    const int ebase = eg * 256;

    float a0 = 0.f, a1 = 0.f;
    #pragma unroll 4
    for (int j = 0; j < 256; j += 4) {
        const int e = ebase + j;
        const float4 w0 = *(const float4*)&wlds[0][e];
        const float4 w1 = *(const float4*)&wlds[1][e];
        const float r0 = eb[(e + 0) * 256];
        const float r1 = eb[(e + 1) * 256];
        const float r2 = eb[(e + 2) * 256];
        const float r3 = eb[(e + 3) * 256];
        a0 = fmaf(w0.x, r0, a0); a0 = fmaf(w0.y, r1, a0);
        a0 = fmaf(w0.z, r2, a0); a0 = fmaf(w0.w, r3, a0);
        a1 = fmaf(w1.x, r0, a1); a1 = fmaf(w1.y, r1, a1);
        a1 = fmaf(w1.z, r2, a1); a1 = fmaf(w1.w, r3, a1);
    }
    part[eg][dl][0] = a0;
    part[eg][dl][1] = a1;
    __syncthreads();

    {
        const int t  = tid >> 7;
        const int d2 = tid & 127;
        const float v = part[0][d2][t] + part[1][d2][t];
        ctx[(bt0 + t) * 256 + dh * 128 + d2] = v;
    }
}

extern "C" void kernel_launch(void* const* d_in, const int* in_sizes, int n_in,
                              void* d_out, int out_size, void* d_ws, size_t ws_size,
                              hipStream_t stream) {
    const float* enc = (const float*)d_in[0];   // [4,512,256]
    const float* dec = (const float*)d_in[1];   // [4,256,256]
    const float* Wa  = (const float*)d_in[2];   // [256,256]
    const float* Ua  = (const float*)d_in[3];   // [256,256]
    const float* Va  = (const float*)d_in[4];   // [256,1]

    float* out = (float*)d_out;
    float* ctx = out;                           // [4,256,256]
    float* aw  = out + B * TD * D;              // [4,256,512]

    float* ewt = (float*)d_ws;                  // [4][256 d][512 e]  2 MB
    float* eu  = ewt + (size_t)B * D * TE;      // [4][256 t][256 d]  1 MB
    float* raw = eu  + (size_t)B * TD * D;      // [4][256 t][512 e]  2 MB

    proj_kernel <<<dim3(768),  dim3(256), 0, stream>>>(enc, dec, Wa, Ua, ewt, eu);
    score_kernel<<<dim3(1024), dim3(256), 0, stream>>>(ewt, eu, Va, raw);
    sctx_kernel <<<dim3(1024), dim3(256), 0, stream>>>(enc, raw, ctx, aw);
}

// Round 6
// 106.643 us; speedup vs baseline: 1.6564x; 1.1016x over previous
//
#include <hip/hip_runtime.h>

#define B 4
#define TE 512
#define TD 256
#define D 256

#define C2    2.8853900817779268f   // 2/ln(2): exp(2x) = exp2(C2*x)
#define LOG2E 1.4426950408889634f

// ---------------------------------------------------------------------------
// K1: projections + exp2.
//   ewt[b][d][e] = exp2(C2 * (enc@W_a)[b][e][d])   (TRANSPOSED, e contiguous)
//   eu [b][t][d] = exp2(C2 * (dec@U_a)[b][t][d])
// Blocks 0..511: enc (4 e-rows).  Blocks 512..767: dec (4 t-rows).
// Thread = output column j (256 cols). Full-K accumulation, no k-split:
// A rows via LDS b128 broadcasts, W via coalesced dword loads.
// Transposed store is a per-thread float4 (4 consecutive e at fixed d).
// ---------------------------------------------------------------------------
__global__ __launch_bounds__(256) void proj_kernel(
    const float* __restrict__ enc, const float* __restrict__ dec,
    const float* __restrict__ Wa,  const float* __restrict__ Ua,
    float* __restrict__ ewt, float* __restrict__ eu)
{
    __shared__ float a_lds[4 * 256];
    const int tid = threadIdx.x;
    const int blk = blockIdx.x;
    const bool is_enc = blk < 512;
    const float* __restrict__ A = is_enc ? enc : dec;
    const float* __restrict__ W = is_enc ? Wa  : Ua;
    const int row0 = (is_enc ? blk : blk - 512) * 4;

    ((float4*)a_lds)[tid] = ((const float4*)(A + (size_t)row0 * 256))[tid];
    __syncthreads();

    float ax = 0.f, ay = 0.f, az = 0.f, aw = 0.f;   // rows row0..row0+3, col=tid

    #pragma unroll 4
    for (int k = 0; k < 256; k += 4) {
        const float w0 = W[(k + 0) * 256 + tid];
        const float w1 = W[(k + 1) * 256 + tid];
        const float w2 = W[(k + 2) * 256 + tid];
        const float w3 = W[(k + 3) * 256 + tid];
        const float4 a0 = *(const float4*)&a_lds[0 * 256 + k];
        const float4 a1 = *(const float4*)&a_lds[1 * 256 + k];
        const float4 a2 = *(const float4*)&a_lds[2 * 256 + k];
        const float4 a3 = *(const float4*)&a_lds[3 * 256 + k];
        ax = fmaf(a0.x, w0, ax); ax = fmaf(a0.y, w1, ax); ax = fmaf(a0.z, w2, ax); ax = fmaf(a0.w, w3, ax);
        ay = fmaf(a1.x, w0, ay); ay = fmaf(a1.y, w1, ay); ay = fmaf(a1.z, w2, ay); ay = fmaf(a1.w, w3, ay);
        az = fmaf(a2.x, w0, az); az = fmaf(a2.y, w1, az); az = fmaf(a2.z, w2, az); az = fmaf(a2.w, w3, az);
        aw = fmaf(a3.x, w0, aw); aw = fmaf(a3.y, w1, aw); aw = fmaf(a3.z, w2, aw); aw = fmaf(a3.w, w3, aw);
    }

    float4 f;
    f.x = __builtin_amdgcn_exp2f(ax * C2);
    f.y = __builtin_amdgcn_exp2f(ay * C2);
    f.z = __builtin_amdgcn_exp2f(az * C2);
    f.w = __builtin_amdgcn_exp2f(aw * C2);

    if (is_enc) {
        const int b  = row0 >> 9;
        const int e0 = row0 & 511;
        *(float4*)&ewt[((size_t)(b * 256 + tid)) * 512 + e0] = f;   // e-contig
    } else {
        eu[(row0 + 0) * 256 + tid] = f.x;
        eu[(row0 + 1) * 256 + tid] = f.y;
        eu[(row0 + 2) * 256 + tid] = f.z;
        eu[(row0 + 3) * 256 + tid] = f.w;
    }
}

// ---------------------------------------------------------------------------
// K2: fused score + softmax + context.  One block per (b, t-quad):
// 256 blocks x 512 threads (8 waves, 1 block/CU).
// Score: thread = e; q_t = sum_d v_d / (1 + Ew[d][e]*Eu[t][d]); the uniform
//        sum_d v_d term is softmax-invariant and dropped (score' = -2q).
// Softmax: 2 waves per t, shuffle reductions, tiny LDS combine.
// Context: thread = (e-group, d); 2-way e-group reduce through LDS.
// ---------------------------------------------------------------------------
__global__ __launch_bounds__(512) void attn_kernel(
    const float* __restrict__ enc, const float* __restrict__ ewt,
    const float* __restrict__ eu,  const float* __restrict__ Va,
    float* __restrict__ ctx, float* __restrict__ aw)
{
    __shared__ float eul[4 * 256];     // 4 Eu rows
    __shared__ float val[256];         // Va
    __shared__ float sc[4][512];       // scores, then weights
    __shared__ float wred[16];         // per-wave max / sum partials
    __shared__ float part[2][4][256];  // ctx e-group partials

    const int tid = threadIdx.x;
    const int b   = blockIdx.x >> 6;
    const int t0  = (blockIdx.x & 63) * 4;
    const int bt0 = b * 256 + t0;          // flat (b,t) base

    if (tid < 256) val[tid] = Va[tid];
    {
        const float* __restrict__ src = eu + (size_t)bt0 * 256;
        eul[tid]       = src[tid];
        eul[tid + 512] = src[tid + 512];
    }
    __syncthreads();

    // ---- scores ---------------------------------------------------------
    const float* __restrict__ ewb = ewt + (size_t)b * 256 * 512 + tid;
    float qx = 0.f, qy = 0.f, qz = 0.f, qw = 0.f;

    #pragma unroll 4
    for (int d = 0; d < 256; d += 4) {
        const float w0 = ewb[(d + 0) * 512];
        const float w1 = ewb[(d + 1) * 512];
        const float w2 = ewb[(d + 2) * 512];
        const float w3 = ewb[(d + 3) * 512];
        const float4 v4 = *(const float4*)&val[d];
        const float4 a0 = *(const float4*)&eul[0 * 256 + d];
        const float4 a1 = *(const float4*)&eul[1 * 256 + d];
        const float4 a2 = *(const float4*)&eul[2 * 256 + d];
        const float4 a3 = *(const float4*)&eul[3 * 256 + d];

        qx += v4.x * __builtin_amdgcn_rcpf(fmaf(w0, a0.x, 1.0f));
        qx += v4.y * __builtin_amdgcn_rcpf(fmaf(w1, a0.y, 1.0f));
        qx += v4.z * __builtin_amdgcn_rcpf(fmaf(w2, a0.z, 1.0f));
        qx += v4.w * __builtin_amdgcn_rcpf(fmaf(w3, a0.w, 1.0f));

        qy += v4.x * __builtin_amdgcn_rcpf(fmaf(w0, a1.x, 1.0f));
        qy += v4.y * __builtin_amdgcn_rcpf(fmaf(w1, a1.y, 1.0f));
        qy += v4.z * __builtin_amdgcn_rcpf(fmaf(w2, a1.z, 1.0f));
        qy += v4.w * __builtin_amdgcn_rcpf(fmaf(w3, a1.w, 1.0f));

        qz += v4.x * __builtin_amdgcn_rcpf(fmaf(w0, a2.x, 1.0f));
        qz += v4.y * __builtin_amdgcn_rcpf(fmaf(w1, a2.y, 1.0f));
        qz += v4.z * __builtin_amdgcn_rcpf(fmaf(w2, a2.z, 1.0f));
        qz += v4.w * __builtin_amdgcn_rcpf(fmaf(w3, a2.w, 1.0f));

        qw += v4.x * __builtin_amdgcn_rcpf(fmaf(w0, a3.x, 1.0f));
        qw += v4.y * __builtin_amdgcn_rcpf(fmaf(w1, a3.y, 1.0f));
        qw += v4.z * __builtin_amdgcn_rcpf(fmaf(w2, a3.z, 1.0f));
        qw += v4.w * __builtin_amdgcn_rcpf(fmaf(w3, a3.w, 1.0f));
    }

    sc[0][tid] = -2.0f * qx;
    sc[1][tid] = -2.0f * qy;
    sc[2][tid] = -2.0f * qz;
    sc[3][tid] = -2.0f * qw;
    __syncthreads();

    // ---- softmax: wave wv handles (t = wv>>1, half = wv&1) --------------
    {
        const int wv   = tid >> 6;
        const int lane = tid & 63;
        const int t    = wv >> 1;
        const int hf   = wv & 1;
        float* __restrict__ srow = &sc[t][hf * 256];

        const float x0 = srow[lane];
        const float x1 = srow[lane + 64];
        const float x2 = srow[lane + 128];
        const float x3 = srow[lane + 192];

        float m = fmaxf(fmaxf(x0, x1), fmaxf(x2, x3));
        #pragma unroll
        for (int s = 32; s > 0; s >>= 1) m = fmaxf(m, __shfl_xor(m, s, 64));
        if (lane == 0) wred[wv] = m;
        __syncthreads();
        const float M = fmaxf(wred[2 * t], wred[2 * t + 1]);

        const float g0 = __builtin_amdgcn_exp2f((x0 - M) * LOG2E);
        const float g1 = __builtin_amdgcn_exp2f((x1 - M) * LOG2E);
        const float g2 = __builtin_amdgcn_exp2f((x2 - M) * LOG2E);
        const float g3 = __builtin_amdgcn_exp2f((x3 - M) * LOG2E);

        float ssum = (g0 + g1) + (g2 + g3);
        #pragma unroll
        for (int s = 32; s > 0; s >>= 1) ssum += __shfl_xor(ssum, s, 64);
        if (lane == 0) wred[8 + wv] = ssum;
        __syncthreads();
        const float inv = __builtin_amdgcn_rcpf(wred[8 + 2 * t] + wred[8 + 2 * t + 1]);

        const float p0 = g0 * inv, p1 = g1 * inv, p2 = g2 * inv, p3 = g3 * inv;
        srow[lane]       = p0;
        srow[lane + 64]  = p1;
        srow[lane + 128] = p2;
        srow[lane + 192] = p3;
        float* __restrict__ ao = aw + ((size_t)(bt0 + t)) * 512 + hf * 256;
        ao[lane]       = p0;
        ao[lane + 64]  = p1;
        ao[lane + 128] = p2;
        ao[lane + 192] = p3;
    }
    __syncthreads();

    // ---- context --------------------------------------------------------
    {
        const int eg = tid >> 8;       // 0..1: e in [eg*256, eg*256+256)
        const int dl = tid & 255;      // d
        const float* __restrict__ eb =
            enc + ((size_t)b * 512 + eg * 256) * 256 + dl;
        const int e0 = eg * 256;

        float cx = 0.f, cy = 0.f, cz = 0.f, cw = 0.f;
        #pragma unroll 4
        for (int j = 0; j < 256; j += 4) {
            const float4 w0 = *(const float4*)&sc[0][e0 + j];
            const float4 w1 = *(const float4*)&sc[1][e0 + j];
            const float4 w2 = *(const float4*)&sc[2][e0 + j];
            const float4 w3 = *(const float4*)&sc[3][e0 + j];
            const float r0 = eb[(j + 0) * 256];
            const float r1 = eb[(j + 1) * 256];
            const float r2 = eb[(j + 2) * 256];
            const float r3 = eb[(j + 3) * 256];
            cx = fmaf(w0.x, r0, cx); cx = fmaf(w0.y, r1, cx); cx = fmaf(w0.z, r2, cx); cx = fmaf(w0.w, r3, cx);
            cy = fmaf(w1.x, r0, cy); cy = fmaf(w1.y, r1, cy); cy = fmaf(w1.z, r2, cy); cy = fmaf(w1.w, r3, cy);
            cz = fmaf(w2.x, r0, cz); cz = fmaf(w2.y, r1, cz); cz = fmaf(w2.z, r2, cz); cz = fmaf(w2.w, r3, cz);
            cw = fmaf(w3.x, r0, cw); cw = fmaf(w3.y, r1, cw); cw = fmaf(w3.z, r2, cw); cw = fmaf(w3.w, r3, cw);
        }
        part[eg][0][dl] = cx;
        part[eg][1][dl] = cy;
        part[eg][2][dl] = cz;
        part[eg][3][dl] = cw;
    }
    __syncthreads();

    {
        const int d2 = tid & 255;
        const int th = tid >> 8;              // 0..1
        #pragma unroll
        for (int p = 0; p < 2; p++) {
            const int t = (p << 1) | th;
            ctx[((size_t)(bt0 + t)) * 256 + d2] =
                part[0][t][d2] + part[1][t][d2];
        }
    }
}

extern "C" void kernel_launch(void* const* d_in, const int* in_sizes, int n_in,
                              void* d_out, int out_size, void* d_ws, size_t ws_size,
                              hipStream_t stream) {
    const float* enc = (const float*)d_in[0];   // [4,512,256]
    const float* dec = (const float*)d_in[1];   // [4,256,256]
    const float* Wa  = (const float*)d_in[2];   // [256,256]
    const float* Ua  = (const float*)d_in[3];   // [256,256]
    const float* Va  = (const float*)d_in[4];   // [256,1]

    float* out = (float*)d_out;
    float* ctx = out;                           // [4,256,256]
    float* aw  = out + B * TD * D;              // [4,256,512]

    float* ewt = (float*)d_ws;                  // [4][256 d][512 e]  2 MB
    float* eu  = ewt + (size_t)B * D * TE;      // [4][256 t][256 d]  1 MB

    proj_kernel<<<dim3(768), dim3(256), 0, stream>>>(enc, dec, Wa, Ua, ewt, eu);
    attn_kernel<<<dim3(256), dim3(512), 0, stream>>>(enc, ewt, eu, Va, ctx, aw);
}